// Round 1
// baseline (339.239 us; speedup 1.0000x reference)
//
#include <hip/hip_runtime.h>
#include <hip/hip_bf16.h>

typedef __attribute__((ext_vector_type(8))) short bf16x8;
typedef __attribute__((ext_vector_type(4))) float f32x4;

#define NB 32
#define NC 256
#define NN 1024

__device__ inline unsigned pack2(float a, float b) {
    __hip_bfloat16 ha = __float2bfloat16(a), hb = __float2bfloat16(b);
    unsigned short ua = *(unsigned short*)&ha, ub = *(unsigned short*)&hb;
    return (unsigned)ua | ((unsigned)ub << 16);
}

// ---------------------------------------------------------------------------
// Kernel 1: QKV projection (fp32 VALU).  qkv[o,n] = sum_c w_in[o,c]*x[b,c,n]+b_in[o]
// Writes Qt/Kt as [b][n][c] bf16, V as [b][c][n] bf16.
// grid (48, 32) = (o-tiles of 16, batch), block 256; each thread: 4 n, 16 o.
// ---------------------------------------------------------------------------
__global__ __launch_bounds__(256) void qkv_proj_kernel(
    const float* __restrict__ x, const float* __restrict__ w_in,
    const float* __restrict__ b_in, __hip_bfloat16* __restrict__ Qt,
    __hip_bfloat16* __restrict__ Kt, __hip_bfloat16* __restrict__ Vx)
{
    __shared__ float w_sT[NC][16];           // [c][o] 16 KB
    __shared__ __hip_bfloat16 t_s[16][NN];   // 32 KB transpose buffer (V path)
    const int t  = threadIdx.x;
    const int o0 = blockIdx.x * 16;
    const int b  = blockIdx.y;

    { // w_sT[c][i] = w_in[o0+i][c]
        const int i = t & 15;
        const int cb = t >> 4;
        #pragma unroll
        for (int it = 0; it < 16; ++it) {
            const int c = cb + it * 16;
            w_sT[c][i] = w_in[(o0 + i) * NC + c];
        }
    }
    __syncthreads();

    float acc[16][4];
    #pragma unroll
    for (int i = 0; i < 16; ++i) {
        const float bv = b_in[o0 + i];
        acc[i][0] = bv; acc[i][1] = bv; acc[i][2] = bv; acc[i][3] = bv;
    }
    const float* xb = x + (size_t)b * NC * NN;
    const int n0 = t * 4;
    for (int c = 0; c < NC; ++c) {
        const float4 xv = *(const float4*)(xb + c * NN + n0);
        const float xa0 = xv.x, xa1 = xv.y, xa2 = xv.z, xa3 = xv.w;
        const float4* wr = (const float4*)(&w_sT[c][0]);
        #pragma unroll
        for (int i4 = 0; i4 < 4; ++i4) {
            const float4 wv = wr[i4];
            acc[i4*4+0][0] += wv.x*xa0; acc[i4*4+0][1] += wv.x*xa1; acc[i4*4+0][2] += wv.x*xa2; acc[i4*4+0][3] += wv.x*xa3;
            acc[i4*4+1][0] += wv.y*xa0; acc[i4*4+1][1] += wv.y*xa1; acc[i4*4+1][2] += wv.y*xa2; acc[i4*4+1][3] += wv.y*xa3;
            acc[i4*4+2][0] += wv.z*xa0; acc[i4*4+2][1] += wv.z*xa1; acc[i4*4+2][2] += wv.z*xa2; acc[i4*4+2][3] += wv.z*xa3;
            acc[i4*4+3][0] += wv.w*xa0; acc[i4*4+3][1] += wv.w*xa1; acc[i4*4+3][2] += wv.w*xa2; acc[i4*4+3][3] += wv.w*xa3;
        }
    }

    if (o0 < 512) {
        // Q or K range: write [b][n][o0..o0+16] bf16, 32 B per (thread,n)
        __hip_bfloat16* dst = (o0 < NC) ? Qt : Kt;
        const int oo = (o0 < NC) ? o0 : (o0 - NC);
        #pragma unroll
        for (int q = 0; q < 4; ++q) {
            const int n = n0 + q;
            uint4 v0, v1;
            v0.x = pack2(acc[0][q],  acc[1][q]);  v0.y = pack2(acc[2][q],  acc[3][q]);
            v0.z = pack2(acc[4][q],  acc[5][q]);  v0.w = pack2(acc[6][q],  acc[7][q]);
            v1.x = pack2(acc[8][q],  acc[9][q]);  v1.y = pack2(acc[10][q], acc[11][q]);
            v1.z = pack2(acc[12][q], acc[13][q]); v1.w = pack2(acc[14][q], acc[15][q]);
            uint4* dp = (uint4*)(dst + ((size_t)b * NN + n) * NC + oo);
            dp[0] = v0; dp[1] = v1;
        }
    } else {
        // V range: transpose via LDS, write [b][c][n] rows coalesced
        #pragma unroll
        for (int i = 0; i < 16; ++i) {
            uint2 v;
            v.x = pack2(acc[i][0], acc[i][1]);
            v.y = pack2(acc[i][2], acc[i][3]);
            *(uint2*)&t_s[i][n0] = v;
        }
        __syncthreads();
        const int co = o0 - 512;
        #pragma unroll
        for (int i = 0; i < 16; ++i) {
            uint2 v = *(uint2*)&t_s[i][t * 4];
            *(uint2*)(Vx + ((size_t)b * NC + co + i) * NN + t * 4) = v;
        }
    }
}

// ---------------------------------------------------------------------------
// Kernel 2: flash attention, bf16 MFMA 16x16x32.
// grid (16, 32) = (64-row query blocks, batch), block 256 = 4 waves x 16 rows.
// ---------------------------------------------------------------------------
__global__ __launch_bounds__(256, 2) void attn_kernel(
    const __hip_bfloat16* __restrict__ Qt, const __hip_bfloat16* __restrict__ Kt,
    const __hip_bfloat16* __restrict__ Vx, __hip_bfloat16* __restrict__ Ht)
{
    __shared__ __hip_bfloat16 K_s[64][264];    // [m][c], row pad +8 -> 33.8 KB
    __shared__ __hip_bfloat16 V_s[256][72];    // [c][m], row pad +8 -> 36.9 KB
    __shared__ __hip_bfloat16 P_s[4][16][72];  // per-wave P tile, 9.2 KB

    const int t  = threadIdx.x;
    const int wv = t >> 6, ln = t & 63;
    const int lo = ln & 15, hi = ln >> 4;
    const int b  = blockIdx.y;
    const int n0 = blockIdx.x * 64;
    const float scale = 0.0625f;  // 1/sqrt(256)

    // Q fragments for this wave's 16 rows: row = lo, k = kk*32 + hi*8 + j
    const __hip_bfloat16* qp = Qt + ((size_t)b * NN + n0 + wv * 16 + lo) * NC;
    bf16x8 qf[8];
    #pragma unroll
    for (int kk = 0; kk < 8; ++kk)
        qf[kk] = *(const bf16x8*)(qp + kk * 32 + hi * 8);

    f32x4 acc[16];
    #pragma unroll
    for (int cf = 0; cf < 16; ++cf) acc[cf] = (f32x4){0.f, 0.f, 0.f, 0.f};
    float mr[4] = {-INFINITY, -INFINITY, -INFINITY, -INFINITY};
    float sr[4] = {0.f, 0.f, 0.f, 0.f};

    for (int mc = 0; mc < 16; ++mc) {
        const int m0 = mc * 64;
        __syncthreads();  // previous iteration's LDS readers done
        // stage K tile: rows m0..m0+64 of Kt[b], 512 B each
        #pragma unroll
        for (int it = 0; it < 8; ++it) {
            const int idx = t + it * 256;
            const int r = idx >> 5, sg = idx & 31;
            *(uint4*)&K_s[r][sg * 8] =
                *(const uint4*)(Kt + ((size_t)b * NN + m0 + r) * NC + sg * 8);
        }
        // stage V tile: all 256 c-rows, cols m0..m0+64
        #pragma unroll
        for (int it = 0; it < 8; ++it) {
            const int idx = t + it * 256;
            const int r = idx >> 3, sg = idx & 7;
            *(uint4*)&V_s[r][sg * 8] =
                *(const uint4*)(Vx + ((size_t)b * NC + r) * NN + m0 + sg * 8);
        }
        __syncthreads();

        // S = Q^T K : 4 m-frags x 8 k-steps
        f32x4 sf[4];
        #pragma unroll
        for (int mf = 0; mf < 4; ++mf) sf[mf] = (f32x4){0.f, 0.f, 0.f, 0.f};
        #pragma unroll
        for (int mf = 0; mf < 4; ++mf) {
            #pragma unroll
            for (int kk = 0; kk < 8; ++kk) {
                bf16x8 kf = *(const bf16x8*)&K_s[mf * 16 + lo][kk * 32 + hi * 8];
                sf[mf] = __builtin_amdgcn_mfma_f32_16x16x32_bf16(qf[kk], kf, sf[mf], 0, 0, 0);
            }
        }

        // online softmax; lane holds rows hi*4+r, col lo (per 16-lane group)
        float al[4];
        #pragma unroll
        for (int r = 0; r < 4; ++r) {
            float tm = fmaxf(fmaxf(sf[0][r], sf[1][r]), fmaxf(sf[2][r], sf[3][r]));
            #pragma unroll
            for (int msk = 1; msk < 16; msk <<= 1)
                tm = fmaxf(tm, __shfl_xor(tm, msk, 64));
            const float mn = fmaxf(mr[r], tm * scale);
            al[r] = __expf(mr[r] - mn);
            mr[r] = mn;
        }
        float p[4][4];
        #pragma unroll
        for (int r = 0; r < 4; ++r) {
            float s = 0.f;
            #pragma unroll
            for (int mf = 0; mf < 4; ++mf) {
                p[mf][r] = __expf(sf[mf][r] * scale - mr[r]);
                s += p[mf][r];
            }
            #pragma unroll
            for (int msk = 1; msk < 16; msk <<= 1)
                s += __shfl_xor(s, msk, 64);
            sr[r] = sr[r] * al[r] + s;
            #pragma unroll
            for (int cf = 0; cf < 16; ++cf) acc[cf][r] *= al[r];
        }
        // P tile to wave-private LDS (C-layout write, A-layout read)
        #pragma unroll
        for (int mf = 0; mf < 4; ++mf)
            #pragma unroll
            for (int r = 0; r < 4; ++r)
                P_s[wv][hi * 4 + r][mf * 16 + lo] = __float2bfloat16(p[mf][r]);
        asm volatile("s_waitcnt lgkmcnt(0)" ::: "memory");

        // H^T += P * V^T : k over 64 keys (2 k-steps), 16 c-frags
        #pragma unroll
        for (int k2 = 0; k2 < 2; ++k2) {
            bf16x8 pf = *(const bf16x8*)&P_s[wv][lo][k2 * 32 + hi * 8];
            #pragma unroll
            for (int cf = 0; cf < 16; ++cf) {
                bf16x8 vf = *(const bf16x8*)&V_s[cf * 16 + lo][k2 * 32 + hi * 8];
                acc[cf] = __builtin_amdgcn_mfma_f32_16x16x32_bf16(pf, vf, acc[cf], 0, 0, 0);
            }
        }
    }

    // epilogue: H^T[n][c] / l_n  -> Ht [b][n][c] bf16
    float inv[4];
    #pragma unroll
    for (int r = 0; r < 4; ++r) inv[r] = 1.0f / sr[r];
    __hip_bfloat16* hb = Ht + ((size_t)b * NN + n0 + wv * 16) * NC;
    #pragma unroll
    for (int cf = 0; cf < 16; ++cf)
        #pragma unroll
        for (int r = 0; r < 4; ++r)
            hb[(size_t)(hi * 4 + r) * NC + cf * 16 + lo] =
                __float2bfloat16(acc[cf][r] * inv[r]);
}

// ---------------------------------------------------------------------------
// Kernel 3: out = w_out @ h + b_out + x   (fp32 VALU)
// grid (8, 2, 32) = (o-tiles of 32, n-halves of 512, batch), block 256.
// Each thread: 2 n (t and t+256 within half), 32 o.
// ---------------------------------------------------------------------------
__global__ __launch_bounds__(256) void out_proj_kernel(
    const float* __restrict__ x, const float* __restrict__ w_out,
    const float* __restrict__ b_out, const __hip_bfloat16* __restrict__ Ht,
    float* __restrict__ out)
{
    __shared__ float w_sT[NC][32];           // [c][o] 32 KB
    __shared__ __hip_bfloat16 h_s[512][18];  // 16-c chunk, odd-word row stride, 18 KB
    const int t  = threadIdx.x;
    const int o0 = blockIdx.x * 32;
    const int nh = blockIdx.y * 512;
    const int b  = blockIdx.z;

    { // w_sT[c][i] = w_out[o0+i][c]
        const int i = t & 31;
        #pragma unroll
        for (int it = 0; it < 32; ++it) {
            const int c = (t >> 5) + it * 8;
            w_sT[c][i] = w_out[(o0 + i) * NC + c];
        }
    }

    float acc0[32], acc1[32];
    #pragma unroll
    for (int i = 0; i < 32; ++i) { acc0[i] = 0.f; acc1[i] = 0.f; }

    for (int cc = 0; cc < 16; ++cc) {
        __syncthreads();  // previous chunk readers done (also orders w_sT load)
        #pragma unroll
        for (int it = 0; it < 4; ++it) {
            const int idx = t + it * 256;
            const int r = idx >> 1, half = idx & 1;
            const uint4 v = *(const uint4*)(Ht + ((size_t)b * NN + nh + r) * NC + cc * 16 + half * 8);
            unsigned* d = (unsigned*)&h_s[r][half * 8];
            d[0] = v.x; d[1] = v.y; d[2] = v.z; d[3] = v.w;
        }
        __syncthreads();
        #pragma unroll
        for (int c = 0; c < 16; ++c) {
            const float h0 = __bfloat162float(h_s[t][c]);
            const float h1 = __bfloat162float(h_s[t + 256][c]);
            const float4* wr = (const float4*)(&w_sT[cc * 16 + c][0]);
            #pragma unroll
            for (int i4 = 0; i4 < 8; ++i4) {
                const float4 wv = wr[i4];
                acc0[i4*4+0] += wv.x*h0; acc1[i4*4+0] += wv.x*h1;
                acc0[i4*4+1] += wv.y*h0; acc1[i4*4+1] += wv.y*h1;
                acc0[i4*4+2] += wv.z*h0; acc1[i4*4+2] += wv.z*h1;
                acc0[i4*4+3] += wv.w*h0; acc1[i4*4+3] += wv.w*h1;
            }
        }
    }

    #pragma unroll
    for (int i = 0; i < 32; ++i) {
        const float bo = b_out[o0 + i];
        const size_t base = ((size_t)b * NC + o0 + i) * NN + nh;
        out[base + t]       = acc0[i] + bo + x[base + t];
        out[base + 256 + t] = acc1[i] + bo + x[base + 256 + t];
    }
}

// ---------------------------------------------------------------------------
extern "C" void kernel_launch(void* const* d_in, const int* in_sizes, int n_in,
                              void* d_out, int out_size, void* d_ws, size_t ws_size,
                              hipStream_t stream) {
    const float* x     = (const float*)d_in[0];
    const float* w_in  = (const float*)d_in[1];
    const float* b_in  = (const float*)d_in[2];
    const float* w_out = (const float*)d_in[3];
    const float* b_out = (const float*)d_in[4];
    float* out = (float*)d_out;

    // workspace layout: Qt | Kt | V | Ht, 16 MB each (bf16), 64 MB total
    if (ws_size < (size_t)64 * 1024 * 1024) return;  // fail loud (output stays poisoned)
    char* ws = (char*)d_ws;
    __hip_bfloat16* Qt = (__hip_bfloat16*)(ws);
    __hip_bfloat16* Kt = (__hip_bfloat16*)(ws + ((size_t)16 << 20));
    __hip_bfloat16* Vx = (__hip_bfloat16*)(ws + ((size_t)32 << 20));
    __hip_bfloat16* Ht = (__hip_bfloat16*)(ws + ((size_t)48 << 20));

    qkv_proj_kernel<<<dim3(48, 32), 256, 0, stream>>>(x, w_in, b_in, Qt, Kt, Vx);
    attn_kernel<<<dim3(16, 32), 256, 0, stream>>>(Qt, Kt, Vx, Ht);
    out_proj_kernel<<<dim3(8, 2, 32), 256, 0, stream>>>(x, w_out, b_out, Ht, out);
}

// Round 2
// 132.708 us; speedup vs baseline: 2.5563x; 2.5563x over previous
//
#include <hip/hip_runtime.h>
#include <hip/hip_bf16.h>

typedef __attribute__((ext_vector_type(8))) short bf16x8;
typedef __attribute__((ext_vector_type(4))) float f32x4;

#define NB 32
#define NC 256
#define NN 1024

__device__ __forceinline__ unsigned pack2(float a, float b) {
    __hip_bfloat16 ha = __float2bfloat16(a), hb = __float2bfloat16(b);
    unsigned short ua = *(unsigned short*)&ha, ub = *(unsigned short*)&hb;
    return (unsigned)ua | ((unsigned)ub << 16);
}

// async global->LDS, 16B per lane; LDS dest = wave-uniform base + lane*16
__device__ __forceinline__ void glds16(const __hip_bfloat16* g, void* lds) {
    __builtin_amdgcn_global_load_lds(
        (const __attribute__((address_space(1))) unsigned int*)g,
        (__attribute__((address_space(3))) unsigned int*)lds, 16, 0, 0);
}

// ---------------------------------------------------------------------------
// Kernel 0: transpose+cast  x[b][c][n] f32 -> Xt[b][n][c] bf16
// grid (16 n-tiles, 4 c-tiles, 32 b), block 256. 64x64 tile via f32 LDS.
// ---------------------------------------------------------------------------
__global__ __launch_bounds__(256) void xpose_kernel(
    const float* __restrict__ x, __hip_bfloat16* __restrict__ Xt)
{
    __shared__ float Ls[64 * 67];
    const int t = threadIdx.x;
    const int n0 = blockIdx.x * 64, c0 = blockIdx.y * 64, b = blockIdx.z;
    const int cl = t >> 4, nl = (t & 15) * 4;
    const float* xb = x + ((size_t)b * NC + c0) * NN + n0;
    #pragma unroll
    for (int q4 = 0; q4 < 4; ++q4) {
        const int c = cl + q4 * 16;
        const float4 v = *(const float4*)(xb + (size_t)c * NN + nl);
        Ls[(nl + 0) * 67 + c] = v.x;
        Ls[(nl + 1) * 67 + c] = v.y;
        Ls[(nl + 2) * 67 + c] = v.z;
        Ls[(nl + 3) * 67 + c] = v.w;
    }
    __syncthreads();
    #pragma unroll
    for (int p = 0; p < 2; ++p) {
        const int idx = p * 256 + t, n = idx >> 3, cs = idx & 7;
        const float* r = &Ls[n * 67 + cs * 8];
        uint4 o;
        o.x = pack2(r[0], r[1]); o.y = pack2(r[2], r[3]);
        o.z = pack2(r[4], r[5]); o.w = pack2(r[6], r[7]);
        *(uint4*)(Xt + ((size_t)b * NN + n0 + n) * NC + c0 + cs * 8) = o;
    }
}

// ---------------------------------------------------------------------------
// Shared GEMM staging: bf16 source -> L1 via global_load_lds (pre-swizzled
// source address, m173 pattern), fp32 source -> cvt bf16 -> L2 via swizzled
// ds_write_b128.  Tile per buffer: [128 rows][64 k] bf16 = 16 KB.
// Swizzle: 16B chunk p within 128B row holds logical chunk p ^ (row&7).
// Trace: logical (row=9,c=37): lch=4,j=5 -> phys 4^1=5; staged by idx=77
// (row 9, pch 5) fetching global chunk 5^1=4 -> c=32..39. Reader kk=1,hi=0:
// lch = 4, phys = 5 -> same bytes. Consistent.
// ---------------------------------------------------------------------------
__device__ __forceinline__ void stage_ab(const __hip_bfloat16* __restrict__ Ag,
                                         const float* __restrict__ Bg,
                                         char* Ad, char* Bd, int ks, int t)
{
    const int srow = t >> 3, spch = t & 7;
    #pragma unroll
    for (int it = 0; it < 4; ++it) {
        const int row = it * 32 + srow;
        const int sw  = row & 7;
        glds16(Ag + (size_t)row * NC + ks * 64 + ((spch ^ sw) << 3),
               Ad + (it * 256 + t) * 16);
        const float* wp = Bg + (size_t)row * NC + ks * 64 + (spch << 3);
        const float4 u0 = *(const float4*)wp;
        const float4 u1 = *(const float4*)(wp + 4);
        uint4 pk;
        pk.x = pack2(u0.x, u0.y); pk.y = pack2(u0.z, u0.w);
        pk.z = pack2(u1.x, u1.y); pk.w = pack2(u1.z, u1.w);
        *(uint4*)(Bd + row * 128 + ((spch ^ sw) << 4)) = pk;
    }
}

// ---------------------------------------------------------------------------
// Kernel 1: QKV projection GEMM (bf16 MFMA).
// D[n][o] = sum_c Xt[n][c] * w_in[o][c]   (per batch; n-tile 128, o-tile 128)
// o-tiles 0,1 -> Qt[n][o]; 2,3 -> Kt; 4,5 -> Vx (LDS-transposed to [o][n]).
// grid (8 n, 6 o, 32 b), block 256 = 4 waves (2x2 of 64x64).
// ---------------------------------------------------------------------------
__global__ __launch_bounds__(256, 2) void qkv_gemm_kernel(
    const __hip_bfloat16* __restrict__ Xt, const float* __restrict__ w_in,
    const float* __restrict__ b_in, __hip_bfloat16* __restrict__ Qt,
    __hip_bfloat16* __restrict__ Kt, __hip_bfloat16* __restrict__ Vx)
{
    __shared__ char smem[65536];
    char* const A0 = smem;
    char* const A1 = smem + 16384;
    char* const B0 = smem + 32768;
    char* const B1 = smem + 49152;

    const int t  = threadIdx.x;
    const int wv = t >> 6, ln = t & 63, lo = ln & 15, hi = ln >> 4;
    const int wm = wv >> 1, wn = wv & 1;
    const int n0 = blockIdx.x * 128, o0 = blockIdx.y * 128, b = blockIdx.z;

    const __hip_bfloat16* Ag = Xt + ((size_t)b * NN + n0) * NC;  // A rows = n
    const float* Bg = w_in + (size_t)o0 * NC;                    // B rows = o

    f32x4 acc[4][4];
    #pragma unroll
    for (int i = 0; i < 4; ++i)
        #pragma unroll
        for (int j = 0; j < 4; ++j) acc[i][j] = (f32x4){0.f, 0.f, 0.f, 0.f};

    int ra[4], rb[4];
    #pragma unroll
    for (int f = 0; f < 4; ++f) { ra[f] = wm * 64 + f * 16 + lo; rb[f] = wn * 64 + f * 16 + lo; }

    stage_ab(Ag, Bg, A0, B0, 0, t);
    __syncthreads();
    #pragma unroll
    for (int ks = 0; ks < 4; ++ks) {
        char* Ac = (ks & 1) ? A1 : A0;
        char* Bc = (ks & 1) ? B1 : B0;
        if (ks < 3)
            stage_ab(Ag, Bg, (ks & 1) ? A0 : A1, (ks & 1) ? B0 : B1, ks + 1, t);
        #pragma unroll
        for (int kk = 0; kk < 2; ++kk) {
            bf16x8 av[4], bv[4];
            #pragma unroll
            for (int f = 0; f < 4; ++f) {
                av[f] = *(const bf16x8*)(Ac + ra[f] * 128 + (((kk << 2) | hi) ^ (ra[f] & 7)) * 16);
                bv[f] = *(const bf16x8*)(Bc + rb[f] * 128 + (((kk << 2) | hi) ^ (rb[f] & 7)) * 16);
            }
            #pragma unroll
            for (int fm = 0; fm < 4; ++fm)
                #pragma unroll
                for (int fn = 0; fn < 4; ++fn)
                    acc[fm][fn] = __builtin_amdgcn_mfma_f32_16x16x32_bf16(
                        av[fm], bv[fn], acc[fm][fn], 0, 0, 0);
        }
        __syncthreads();
    }

    float bias[4];
    #pragma unroll
    for (int fn = 0; fn < 4; ++fn) bias[fn] = b_in[o0 + wn * 64 + fn * 16 + lo];

    __hip_bfloat16* Ls = (__hip_bfloat16*)smem;  // [128][136] bf16 = 34 KB
    if (o0 < 512) {
        // Q/K: repack D[n][o] -> rows of [n][c], coalesced 16B stores
        #pragma unroll
        for (int fm = 0; fm < 4; ++fm)
            #pragma unroll
            for (int fn = 0; fn < 4; ++fn)
                #pragma unroll
                for (int r = 0; r < 4; ++r)
                    Ls[(wm * 64 + fm * 16 + hi * 4 + r) * 136 + wn * 64 + fn * 16 + lo] =
                        __float2bfloat16(acc[fm][fn][r] + bias[fn]);
        __syncthreads();
        __hip_bfloat16* dst = (o0 < 256) ? Qt : Kt;
        const int oc = (o0 < 256) ? o0 : o0 - 256;
        #pragma unroll
        for (int p = 0; p < 8; ++p) {
            const int idx = p * 256 + t, row = idx >> 4, ch = idx & 15;
            *(uint4*)(dst + ((size_t)b * NN + n0 + row) * NC + oc + ch * 8) =
                *(const uint4*)&Ls[row * 136 + ch * 8];
        }
    } else {
        // V: transpose to [o][n] rows -> Vx[b][c_out][n]
        #pragma unroll
        for (int fm = 0; fm < 4; ++fm)
            #pragma unroll
            for (int fn = 0; fn < 4; ++fn)
                #pragma unroll
                for (int r = 0; r < 4; ++r)
                    Ls[(wn * 64 + fn * 16 + lo) * 136 + wm * 64 + fm * 16 + hi * 4 + r] =
                        __float2bfloat16(acc[fm][fn][r] + bias[fn]);
        __syncthreads();
        #pragma unroll
        for (int p = 0; p < 8; ++p) {
            const int idx = p * 256 + t, row = idx >> 4, ch = idx & 15;
            *(uint4*)(Vx + ((size_t)b * NC + (o0 - 512) + row) * NN + n0 + ch * 8) =
                *(const uint4*)&Ls[row * 136 + ch * 8];
        }
    }
}

// ---------------------------------------------------------------------------
// Kernel 2: flash attention, bf16 MFMA 16x16x32 (round-1 proven, unchanged).
// grid (16, 32) = (64-row query blocks, batch), block 256 = 4 waves x 16 rows.
// ---------------------------------------------------------------------------
__global__ __launch_bounds__(256, 2) void attn_kernel(
    const __hip_bfloat16* __restrict__ Qt, const __hip_bfloat16* __restrict__ Kt,
    const __hip_bfloat16* __restrict__ Vx, __hip_bfloat16* __restrict__ Ht)
{
    __shared__ __hip_bfloat16 K_s[64][264];    // [m][c], row pad +8 -> 33.8 KB
    __shared__ __hip_bfloat16 V_s[256][72];    // [c][m], row pad +8 -> 36.9 KB
    __shared__ __hip_bfloat16 P_s[4][16][72];  // per-wave P tile, 9.2 KB

    const int t  = threadIdx.x;
    const int wv = t >> 6, ln = t & 63;
    const int lo = ln & 15, hi = ln >> 4;
    const int b  = blockIdx.y;
    const int n0 = blockIdx.x * 64;
    const float scale = 0.0625f;  // 1/sqrt(256)

    const __hip_bfloat16* qp = Qt + ((size_t)b * NN + n0 + wv * 16 + lo) * NC;
    bf16x8 qf[8];
    #pragma unroll
    for (int kk = 0; kk < 8; ++kk)
        qf[kk] = *(const bf16x8*)(qp + kk * 32 + hi * 8);

    f32x4 acc[16];
    #pragma unroll
    for (int cf = 0; cf < 16; ++cf) acc[cf] = (f32x4){0.f, 0.f, 0.f, 0.f};
    float mr[4] = {-INFINITY, -INFINITY, -INFINITY, -INFINITY};
    float sr[4] = {0.f, 0.f, 0.f, 0.f};

    for (int mc = 0; mc < 16; ++mc) {
        const int m0 = mc * 64;
        __syncthreads();
        #pragma unroll
        for (int it = 0; it < 8; ++it) {
            const int idx = t + it * 256;
            const int r = idx >> 5, sg = idx & 31;
            *(uint4*)&K_s[r][sg * 8] =
                *(const uint4*)(Kt + ((size_t)b * NN + m0 + r) * NC + sg * 8);
        }
        #pragma unroll
        for (int it = 0; it < 8; ++it) {
            const int idx = t + it * 256;
            const int r = idx >> 3, sg = idx & 7;
            *(uint4*)&V_s[r][sg * 8] =
                *(const uint4*)(Vx + ((size_t)b * NC + r) * NN + m0 + sg * 8);
        }
        __syncthreads();

        f32x4 sf[4];
        #pragma unroll
        for (int mf = 0; mf < 4; ++mf) sf[mf] = (f32x4){0.f, 0.f, 0.f, 0.f};
        #pragma unroll
        for (int mf = 0; mf < 4; ++mf) {
            #pragma unroll
            for (int kk = 0; kk < 8; ++kk) {
                bf16x8 kf = *(const bf16x8*)&K_s[mf * 16 + lo][kk * 32 + hi * 8];
                sf[mf] = __builtin_amdgcn_mfma_f32_16x16x32_bf16(qf[kk], kf, sf[mf], 0, 0, 0);
            }
        }

        float al[4];
        #pragma unroll
        for (int r = 0; r < 4; ++r) {
            float tm = fmaxf(fmaxf(sf[0][r], sf[1][r]), fmaxf(sf[2][r], sf[3][r]));
            #pragma unroll
            for (int msk = 1; msk < 16; msk <<= 1)
                tm = fmaxf(tm, __shfl_xor(tm, msk, 64));
            const float mn = fmaxf(mr[r], tm * scale);
            al[r] = __expf(mr[r] - mn);
            mr[r] = mn;
        }
        float p[4][4];
        #pragma unroll
        for (int r = 0; r < 4; ++r) {
            float s = 0.f;
            #pragma unroll
            for (int mf = 0; mf < 4; ++mf) {
                p[mf][r] = __expf(sf[mf][r] * scale - mr[r]);
                s += p[mf][r];
            }
            #pragma unroll
            for (int msk = 1; msk < 16; msk <<= 1)
                s += __shfl_xor(s, msk, 64);
            sr[r] = sr[r] * al[r] + s;
            #pragma unroll
            for (int cf = 0; cf < 16; ++cf) acc[cf][r] *= al[r];
        }
        #pragma unroll
        for (int mf = 0; mf < 4; ++mf)
            #pragma unroll
            for (int r = 0; r < 4; ++r)
                P_s[wv][hi * 4 + r][mf * 16 + lo] = __float2bfloat16(p[mf][r]);
        asm volatile("s_waitcnt lgkmcnt(0)" ::: "memory");

        #pragma unroll
        for (int k2 = 0; k2 < 2; ++k2) {
            bf16x8 pf = *(const bf16x8*)&P_s[wv][lo][k2 * 32 + hi * 8];
            #pragma unroll
            for (int cf = 0; cf < 16; ++cf) {
                bf16x8 vf = *(const bf16x8*)&V_s[cf * 16 + lo][k2 * 32 + hi * 8];
                acc[cf] = __builtin_amdgcn_mfma_f32_16x16x32_bf16(pf, vf, acc[cf], 0, 0, 0);
            }
        }
    }

    float inv[4];
    #pragma unroll
    for (int r = 0; r < 4; ++r) inv[r] = 1.0f / sr[r];
    __hip_bfloat16* hb = Ht + ((size_t)b * NN + n0 + wv * 16) * NC;
    #pragma unroll
    for (int cf = 0; cf < 16; ++cf)
        #pragma unroll
        for (int r = 0; r < 4; ++r)
            hb[(size_t)(hi * 4 + r) * NC + cf * 16 + lo] =
                __float2bfloat16(acc[cf][r] * inv[r]);
}

// ---------------------------------------------------------------------------
// Kernel 3: output projection GEMM (bf16 MFMA) + bias + skip.
// D[o][n] = sum_c w_out[o][c] * Ht[n][c];  out = D + b_out + x  (fp32)
// grid (8 n, 2 o, 32 b), block 256 = 4 waves (2x2 of 64x64).
// A = w_out (fp32, reg-staged cvt), B = Ht (bf16, glds).
// ---------------------------------------------------------------------------
__global__ __launch_bounds__(256, 2) void out_gemm_kernel(
    const __hip_bfloat16* __restrict__ Ht, const float* __restrict__ w_out,
    const float* __restrict__ b_out, const float* __restrict__ x,
    float* __restrict__ out)
{
    __shared__ char smem[65536];
    char* const A0 = smem;
    char* const A1 = smem + 16384;
    char* const B0 = smem + 32768;
    char* const B1 = smem + 49152;

    const int t  = threadIdx.x;
    const int wv = t >> 6, ln = t & 63, lo = ln & 15, hi = ln >> 4;
    const int wm = wv >> 1, wn = wv & 1;
    const int n0 = blockIdx.x * 128, o0 = blockIdx.y * 128, b = blockIdx.z;

    const float* Ag = w_out + (size_t)o0 * NC;                    // A rows = o (fp32)
    const __hip_bfloat16* Bg = Ht + ((size_t)b * NN + n0) * NC;   // B rows = n (bf16)

    f32x4 acc[4][4];
    #pragma unroll
    for (int i = 0; i < 4; ++i)
        #pragma unroll
        for (int j = 0; j < 4; ++j) acc[i][j] = (f32x4){0.f, 0.f, 0.f, 0.f};

    int ra[4], rb[4];
    #pragma unroll
    for (int f = 0; f < 4; ++f) { ra[f] = wm * 64 + f * 16 + lo; rb[f] = wn * 64 + f * 16 + lo; }

    stage_ab(Bg, Ag, B0, A0, 0, t);   // bf16 src -> B-tile, fp32 src -> A-tile
    __syncthreads();
    #pragma unroll
    for (int ks = 0; ks < 4; ++ks) {
        char* Ac = (ks & 1) ? A1 : A0;
        char* Bc = (ks & 1) ? B1 : B0;
        if (ks < 3)
            stage_ab(Bg, Ag, (ks & 1) ? B0 : B1, (ks & 1) ? A0 : A1, ks + 1, t);
        #pragma unroll
        for (int kk = 0; kk < 2; ++kk) {
            bf16x8 av[4], bv[4];
            #pragma unroll
            for (int f = 0; f < 4; ++f) {
                av[f] = *(const bf16x8*)(Ac + ra[f] * 128 + (((kk << 2) | hi) ^ (ra[f] & 7)) * 16);
                bv[f] = *(const bf16x8*)(Bc + rb[f] * 128 + (((kk << 2) | hi) ^ (rb[f] & 7)) * 16);
            }
            #pragma unroll
            for (int fm = 0; fm < 4; ++fm)
                #pragma unroll
                for (int fn = 0; fn < 4; ++fn)
                    acc[fm][fn] = __builtin_amdgcn_mfma_f32_16x16x32_bf16(
                        av[fm], bv[fn], acc[fm][fn], 0, 0, 0);
        }
        __syncthreads();
    }

    #pragma unroll
    for (int fm = 0; fm < 4; ++fm) {
        #pragma unroll
        for (int r = 0; r < 4; ++r) {
            const int o = o0 + wm * 64 + fm * 16 + hi * 4 + r;
            const float bo = b_out[o];
            const size_t rowg = ((size_t)b * NC + o) * NN + n0;
            #pragma unroll
            for (int fn = 0; fn < 4; ++fn) {
                const size_t gi = rowg + wn * 64 + fn * 16 + lo;
                out[gi] = acc[fm][fn][r] + bo + x[gi];
            }
        }
    }
}

// ---------------------------------------------------------------------------
extern "C" void kernel_launch(void* const* d_in, const int* in_sizes, int n_in,
                              void* d_out, int out_size, void* d_ws, size_t ws_size,
                              hipStream_t stream) {
    const float* x     = (const float*)d_in[0];
    const float* w_in  = (const float*)d_in[1];
    const float* b_in  = (const float*)d_in[2];
    const float* w_out = (const float*)d_in[3];
    const float* b_out = (const float*)d_in[4];
    float* out = (float*)d_out;

    // workspace: Qt | Kt | Vx | Xt(=Ht after attn), 16 MB each (bf16)
    if (ws_size < (size_t)64 * 1024 * 1024) return;  // fail loud
    char* ws = (char*)d_ws;
    __hip_bfloat16* Qt = (__hip_bfloat16*)(ws);
    __hip_bfloat16* Kt = (__hip_bfloat16*)(ws + ((size_t)16 << 20));
    __hip_bfloat16* Vx = (__hip_bfloat16*)(ws + ((size_t)32 << 20));
    __hip_bfloat16* Xt = (__hip_bfloat16*)(ws + ((size_t)48 << 20));  // aliased as Ht
    __hip_bfloat16* Ht = Xt;  // Xt is dead after qkv_gemm

    xpose_kernel<<<dim3(16, 4, 32), 256, 0, stream>>>(x, Xt);
    qkv_gemm_kernel<<<dim3(8, 6, 32), 256, 0, stream>>>(Xt, w_in, b_in, Qt, Kt, Vx);
    attn_kernel<<<dim3(16, 32), 256, 0, stream>>>(Qt, Kt, Vx, Ht);
    out_gemm_kernel<<<dim3(8, 2, 32), 256, 0, stream>>>(Ht, w_out, b_out, x, out);
}

// Round 3
// 117.217 us; speedup vs baseline: 2.8941x; 1.1322x over previous
//
#include <hip/hip_runtime.h>
#include <hip/hip_bf16.h>

typedef __attribute__((ext_vector_type(8))) short bf16x8;
typedef __attribute__((ext_vector_type(4))) float f32x4;

#define NB 32
#define NC 256
#define NN 1024

__device__ __forceinline__ unsigned pack2(float a, float b) {
    __hip_bfloat16 ha = __float2bfloat16(a), hb = __float2bfloat16(b);
    unsigned short ua = *(unsigned short*)&ha, ub = *(unsigned short*)&hb;
    return (unsigned)ua | ((unsigned)ub << 16);
}

// async global->LDS, 16B per lane; LDS dest = wave-uniform base + lane*16
__device__ __forceinline__ void glds16(const __hip_bfloat16* g, void* lds) {
    __builtin_amdgcn_global_load_lds(
        (const __attribute__((address_space(1))) unsigned int*)g,
        (__attribute__((address_space(3))) unsigned int*)lds, 16, 0, 0);
}

// ---------------------------------------------------------------------------
// Kernel 0: transpose+cast  x[b][c][n] f32 -> Xt[b][n][c] bf16
// ---------------------------------------------------------------------------
__global__ __launch_bounds__(256) void xpose_kernel(
    const float* __restrict__ x, __hip_bfloat16* __restrict__ Xt)
{
    __shared__ float Ls[64 * 67];
    const int t = threadIdx.x;
    const int n0 = blockIdx.x * 64, c0 = blockIdx.y * 64, b = blockIdx.z;
    const int cl = t >> 4, nl = (t & 15) * 4;
    const float* xb = x + ((size_t)b * NC + c0) * NN + n0;
    #pragma unroll
    for (int q4 = 0; q4 < 4; ++q4) {
        const int c = cl + q4 * 16;
        const float4 v = *(const float4*)(xb + (size_t)c * NN + nl);
        Ls[(nl + 0) * 67 + c] = v.x;
        Ls[(nl + 1) * 67 + c] = v.y;
        Ls[(nl + 2) * 67 + c] = v.z;
        Ls[(nl + 3) * 67 + c] = v.w;
    }
    __syncthreads();
    #pragma unroll
    for (int p = 0; p < 2; ++p) {
        const int idx = p * 256 + t, n = idx >> 3, cs = idx & 7;
        const float* r = &Ls[n * 67 + cs * 8];
        uint4 o;
        o.x = pack2(r[0], r[1]); o.y = pack2(r[2], r[3]);
        o.z = pack2(r[4], r[5]); o.w = pack2(r[6], r[7]);
        *(uint4*)(Xt + ((size_t)b * NN + n0 + n) * NC + c0 + cs * 8) = o;
    }
}

// ---------------------------------------------------------------------------
// Shared GEMM staging (unchanged from round 2; element-traced swizzle).
// ---------------------------------------------------------------------------
__device__ __forceinline__ void stage_ab(const __hip_bfloat16* __restrict__ Ag,
                                         const float* __restrict__ Bg,
                                         char* Ad, char* Bd, int ks, int t)
{
    const int srow = t >> 3, spch = t & 7;
    #pragma unroll
    for (int it = 0; it < 4; ++it) {
        const int row = it * 32 + srow;
        const int sw  = row & 7;
        glds16(Ag + (size_t)row * NC + ks * 64 + ((spch ^ sw) << 3),
               Ad + (it * 256 + t) * 16);
        const float* wp = Bg + (size_t)row * NC + ks * 64 + (spch << 3);
        const float4 u0 = *(const float4*)wp;
        const float4 u1 = *(const float4*)(wp + 4);
        uint4 pk;
        pk.x = pack2(u0.x, u0.y); pk.y = pack2(u0.z, u0.w);
        pk.z = pack2(u1.x, u1.y); pk.w = pack2(u1.z, u1.w);
        *(uint4*)(Bd + row * 128 + ((spch ^ sw) << 4)) = pk;
    }
}

// ---------------------------------------------------------------------------
// Kernel 1: QKV projection GEMM (bf16 MFMA) — unchanged from round 2.
// ---------------------------------------------------------------------------
__global__ __launch_bounds__(256, 2) void qkv_gemm_kernel(
    const __hip_bfloat16* __restrict__ Xt, const float* __restrict__ w_in,
    const float* __restrict__ b_in, __hip_bfloat16* __restrict__ Qt,
    __hip_bfloat16* __restrict__ Kt, __hip_bfloat16* __restrict__ Vx)
{
    __shared__ char smem[65536];
    char* const A0 = smem;
    char* const A1 = smem + 16384;
    char* const B0 = smem + 32768;
    char* const B1 = smem + 49152;

    const int t  = threadIdx.x;
    const int wv = t >> 6, ln = t & 63, lo = ln & 15, hi = ln >> 4;
    const int wm = wv >> 1, wn = wv & 1;
    const int n0 = blockIdx.x * 128, o0 = blockIdx.y * 128, b = blockIdx.z;

    const __hip_bfloat16* Ag = Xt + ((size_t)b * NN + n0) * NC;
    const float* Bg = w_in + (size_t)o0 * NC;

    f32x4 acc[4][4];
    #pragma unroll
    for (int i = 0; i < 4; ++i)
        #pragma unroll
        for (int j = 0; j < 4; ++j) acc[i][j] = (f32x4){0.f, 0.f, 0.f, 0.f};

    int ra[4], rb[4];
    #pragma unroll
    for (int f = 0; f < 4; ++f) { ra[f] = wm * 64 + f * 16 + lo; rb[f] = wn * 64 + f * 16 + lo; }

    stage_ab(Ag, Bg, A0, B0, 0, t);
    __syncthreads();
    #pragma unroll
    for (int ks = 0; ks < 4; ++ks) {
        char* Ac = (ks & 1) ? A1 : A0;
        char* Bc = (ks & 1) ? B1 : B0;
        if (ks < 3)
            stage_ab(Ag, Bg, (ks & 1) ? A0 : A1, (ks & 1) ? B0 : B1, ks + 1, t);
        #pragma unroll
        for (int kk = 0; kk < 2; ++kk) {
            bf16x8 av[4], bv[4];
            #pragma unroll
            for (int f = 0; f < 4; ++f) {
                av[f] = *(const bf16x8*)(Ac + ra[f] * 128 + (((kk << 2) | hi) ^ (ra[f] & 7)) * 16);
                bv[f] = *(const bf16x8*)(Bc + rb[f] * 128 + (((kk << 2) | hi) ^ (rb[f] & 7)) * 16);
            }
            #pragma unroll
            for (int fm = 0; fm < 4; ++fm)
                #pragma unroll
                for (int fn = 0; fn < 4; ++fn)
                    acc[fm][fn] = __builtin_amdgcn_mfma_f32_16x16x32_bf16(
                        av[fm], bv[fn], acc[fm][fn], 0, 0, 0);
        }
        __syncthreads();
    }

    float bias[4];
    #pragma unroll
    for (int fn = 0; fn < 4; ++fn) bias[fn] = b_in[o0 + wn * 64 + fn * 16 + lo];

    __hip_bfloat16* Ls = (__hip_bfloat16*)smem;  // [128][136] bf16
    if (o0 < 512) {
        #pragma unroll
        for (int fm = 0; fm < 4; ++fm)
            #pragma unroll
            for (int fn = 0; fn < 4; ++fn)
                #pragma unroll
                for (int r = 0; r < 4; ++r)
                    Ls[(wm * 64 + fm * 16 + hi * 4 + r) * 136 + wn * 64 + fn * 16 + lo] =
                        __float2bfloat16(acc[fm][fn][r] + bias[fn]);
        __syncthreads();
        __hip_bfloat16* dst = (o0 < 256) ? Qt : Kt;
        const int oc = (o0 < 256) ? o0 : o0 - 256;
        #pragma unroll
        for (int p = 0; p < 8; ++p) {
            const int idx = p * 256 + t, row = idx >> 4, ch = idx & 15;
            *(uint4*)(dst + ((size_t)b * NN + n0 + row) * NC + oc + ch * 8) =
                *(const uint4*)&Ls[row * 136 + ch * 8];
        }
    } else {
        #pragma unroll
        for (int fm = 0; fm < 4; ++fm)
            #pragma unroll
            for (int fn = 0; fn < 4; ++fn)
                #pragma unroll
                for (int r = 0; r < 4; ++r)
                    Ls[(wn * 64 + fn * 16 + lo) * 136 + wm * 64 + fm * 16 + hi * 4 + r] =
                        __float2bfloat16(acc[fm][fn][r] + bias[fn]);
        __syncthreads();
        #pragma unroll
        for (int p = 0; p < 8; ++p) {
            const int idx = p * 256 + t, row = idx >> 4, ch = idx & 15;
            *(uint4*)(Vx + ((size_t)b * NC + (o0 - 512) + row) * NN + n0 + ch * 8) =
                *(const uint4*)&Ls[row * 136 + ch * 8];
        }
    }
}

// ---------------------------------------------------------------------------
// Kernel 2: flash attention v2 — 8 waves, QBLK=128, double-buffered glds
// staging with XOR-swizzled K/V tiles, XCD batch affinity, defer-max.
// grid (8,32) -> wid swizzled so each XCD owns 4 whole batches.
// LDS: K[2][64][256] | V[2][256][64] (linear, source-swizzled) | P[8][16][72]
// Swizzle traces (verified):
//   K logical (row5,chunk9): read pc=(9&24)|((9^5)&7)=12; stage idx=5*32+12
//     fetches src chunk (12&24)|((12^5)&7)=9. Match.
//   V logical (row37,chunk5): read pc=5^(37&7)=0; stage idx=37*8+0 fetches
//     src chunk 0^5=5. Match.
// ---------------------------------------------------------------------------
__device__ __forceinline__ void attn_stage(const __hip_bfloat16* __restrict__ Kbase,
                                           const __hip_bfloat16* __restrict__ Vbase,
                                           char* Kd, char* Vd, int m0, int t)
{
    #pragma unroll
    for (int p = 0; p < 4; ++p) {
        const int idx = p * 512 + t;
        const int row = idx >> 5, pc = idx & 31;
        const int sc = (pc & 24) | ((pc ^ row) & 7);
        glds16(Kbase + (size_t)(m0 + row) * NC + sc * 8, Kd + idx * 16);
    }
    #pragma unroll
    for (int p = 0; p < 4; ++p) {
        const int idx = p * 512 + t;
        const int row = idx >> 3, pc = idx & 7;
        const int sc = pc ^ (row & 7);
        glds16(Vbase + (size_t)row * NN + m0 + sc * 8, Vd + idx * 16);
    }
}

__global__ __launch_bounds__(512, 2) void attn_kernel(
    const __hip_bfloat16* __restrict__ Qt, const __hip_bfloat16* __restrict__ Kt,
    const __hip_bfloat16* __restrict__ Vx, __hip_bfloat16* __restrict__ Ht)
{
    __shared__ char smem[149504];   // 2*32768 K | 2*32768 V | 18432 P

    const int t  = threadIdx.x;
    const int wv = t >> 6, ln = t & 63, lo = ln & 15, hi = ln >> 4;
    const int wid = blockIdx.x + 8 * blockIdx.y;       // dispatch-linear id
    const int swz = (wid & 7) * 32 + (wid >> 3);       // XCD gets 4 batches
    const int qb = swz & 7, b = swz >> 3;
    const int n0 = qb * 128;
    const float scale = 0.0625f;  // 1/sqrt(256)

    const __hip_bfloat16* Kbase = Kt + (size_t)b * NN * NC;
    const __hip_bfloat16* Vbase = Vx + (size_t)b * NC * NN;
    __hip_bfloat16* const P_s = (__hip_bfloat16*)(smem + 131072);

    // Q fragments: wave's 16 rows; row=lo, k = kk*32+hi*8+j
    const __hip_bfloat16* qp = Qt + ((size_t)b * NN + n0 + wv * 16 + lo) * NC;
    bf16x8 qf[8];
    #pragma unroll
    for (int kk = 0; kk < 8; ++kk)
        qf[kk] = *(const bf16x8*)(qp + kk * 32 + hi * 8);

    f32x4 acc[16];
    #pragma unroll
    for (int cf = 0; cf < 16; ++cf) acc[cf] = (f32x4){0.f, 0.f, 0.f, 0.f};
    float mr[4] = {-INFINITY, -INFINITY, -INFINITY, -INFINITY};
    float sr[4] = {0.f, 0.f, 0.f, 0.f};

    attn_stage(Kbase, Vbase, smem, smem + 65536, 0, t);
    __syncthreads();   // drains vmcnt -> tile 0 resident

    for (int mc = 0; mc < 16; ++mc) {
        const int cb = mc & 1;
        char* const Kc = smem + cb * 32768;
        char* const Vc = smem + 65536 + cb * 32768;
        if (mc < 15)
            attn_stage(Kbase, Vbase, smem + (cb ^ 1) * 32768,
                       smem + 65536 + (cb ^ 1) * 32768, (mc + 1) * 64, t);

        // S = Q K^T
        f32x4 sf[4];
        #pragma unroll
        for (int mf = 0; mf < 4; ++mf) sf[mf] = (f32x4){0.f, 0.f, 0.f, 0.f};
        __builtin_amdgcn_s_setprio(1);
        #pragma unroll
        for (int mf = 0; mf < 4; ++mf) {
            const int row = mf * 16 + lo;
            #pragma unroll
            for (int kk = 0; kk < 8; ++kk) {
                const int c  = kk * 4 + hi;
                const int pc = (c & 24) | ((c ^ row) & 7);
                bf16x8 kf = *(const bf16x8*)(Kc + row * 512 + pc * 16);
                sf[mf] = __builtin_amdgcn_mfma_f32_16x16x32_bf16(qf[kk], kf, sf[mf], 0, 0, 0);
            }
        }
        __builtin_amdgcn_s_setprio(0);

        // online softmax (defer-max, THR=8); lane: rows hi*4+r, key col mf*16+lo
        float p[4][4];
        #pragma unroll
        for (int r = 0; r < 4; ++r) {
            float tm = fmaxf(fmaxf(sf[0][r], sf[1][r]), fmaxf(sf[2][r], sf[3][r]));
            #pragma unroll
            for (int msk = 1; msk < 16; msk <<= 1)
                tm = fmaxf(tm, __shfl_xor(tm, msk, 64));
            tm *= scale;
            if (__any(tm > mr[r] + 8.f)) {
                const float mn = fmaxf(mr[r], tm);
                const float al = __expf(mr[r] - mn);
                mr[r] = mn;
                sr[r] *= al;
                #pragma unroll
                for (int cf = 0; cf < 16; ++cf) acc[cf][r] *= al;
            }
            float s = 0.f;
            #pragma unroll
            for (int mf = 0; mf < 4; ++mf) {
                p[mf][r] = __expf(sf[mf][r] * scale - mr[r]);
                s += p[mf][r];
            }
            #pragma unroll
            for (int msk = 1; msk < 16; msk <<= 1)
                s += __shfl_xor(s, msk, 64);
            sr[r] += s;
        }
        #pragma unroll
        for (int mf = 0; mf < 4; ++mf)
            #pragma unroll
            for (int r = 0; r < 4; ++r)
                P_s[wv * 1152 + (hi * 4 + r) * 72 + mf * 16 + lo] = __float2bfloat16(p[mf][r]);
        asm volatile("s_waitcnt lgkmcnt(0)" ::: "memory");
        __builtin_amdgcn_sched_barrier(0);

        // H^T += P V^T
        __builtin_amdgcn_s_setprio(1);
        #pragma unroll
        for (int k2 = 0; k2 < 2; ++k2) {
            bf16x8 pf = *(const bf16x8*)&P_s[wv * 1152 + lo * 72 + k2 * 32 + hi * 8];
            #pragma unroll
            for (int cf = 0; cf < 16; ++cf) {
                const int row = cf * 16 + lo;
                const int pc  = (k2 * 4 + hi) ^ (row & 7);
                bf16x8 vf = *(const bf16x8*)(Vc + row * 128 + pc * 16);
                acc[cf] = __builtin_amdgcn_mfma_f32_16x16x32_bf16(pf, vf, acc[cf], 0, 0, 0);
            }
        }
        __builtin_amdgcn_s_setprio(0);
        __syncthreads();  // drains vmcnt(0): next tile resident; buffers swappable
    }

    // epilogue: repack via LDS (K/V buffers dead), coalesced 16B stores
    float inv[4];
    #pragma unroll
    for (int r = 0; r < 4; ++r) inv[r] = 1.0f / sr[r];
    __hip_bfloat16* W = (__hip_bfloat16*)(smem + wv * 8192);  // wave-private [16][256]
    #pragma unroll
    for (int cf = 0; cf < 16; ++cf)
        #pragma unroll
        for (int r = 0; r < 4; ++r)
            W[(hi * 4 + r) * 256 + cf * 16 + lo] = __float2bfloat16(acc[cf][r] * inv[r]);
    asm volatile("s_waitcnt lgkmcnt(0)" ::: "memory");
    __builtin_amdgcn_sched_barrier(0);
    __hip_bfloat16* hrow0 = Ht + ((size_t)b * NN + n0 + wv * 16) * NC;
    #pragma unroll
    for (int pq = 0; pq < 8; ++pq) {
        const int idx = pq * 64 + ln;
        const int row = idx >> 5, ch = idx & 31;
        *(uint4*)(hrow0 + (size_t)row * NC + ch * 8) = *(const uint4*)&W[row * 256 + ch * 8];
    }
}

// ---------------------------------------------------------------------------
// Kernel 3: output projection GEMM (bf16 MFMA) + bias + skip — unchanged.
// ---------------------------------------------------------------------------
__global__ __launch_bounds__(256, 2) void out_gemm_kernel(
    const __hip_bfloat16* __restrict__ Ht, const float* __restrict__ w_out,
    const float* __restrict__ b_out, const float* __restrict__ x,
    float* __restrict__ out)
{
    __shared__ char smem[65536];
    char* const A0 = smem;
    char* const A1 = smem + 16384;
    char* const B0 = smem + 32768;
    char* const B1 = smem + 49152;

    const int t  = threadIdx.x;
    const int wv = t >> 6, ln = t & 63, lo = ln & 15, hi = ln >> 4;
    const int wm = wv >> 1, wn = wv & 1;
    const int n0 = blockIdx.x * 128, o0 = blockIdx.y * 128, b = blockIdx.z;

    const float* Ag = w_out + (size_t)o0 * NC;
    const __hip_bfloat16* Bg = Ht + ((size_t)b * NN + n0) * NC;

    f32x4 acc[4][4];
    #pragma unroll
    for (int i = 0; i < 4; ++i)
        #pragma unroll
        for (int j = 0; j < 4; ++j) acc[i][j] = (f32x4){0.f, 0.f, 0.f, 0.f};

    int ra[4], rb[4];
    #pragma unroll
    for (int f = 0; f < 4; ++f) { ra[f] = wm * 64 + f * 16 + lo; rb[f] = wn * 64 + f * 16 + lo; }

    stage_ab(Bg, Ag, B0, A0, 0, t);
    __syncthreads();
    #pragma unroll
    for (int ks = 0; ks < 4; ++ks) {
        char* Ac = (ks & 1) ? A1 : A0;
        char* Bc = (ks & 1) ? B1 : B0;
        if (ks < 3)
            stage_ab(Bg, Ag, (ks & 1) ? B0 : B1, (ks & 1) ? A0 : A1, ks + 1, t);
        #pragma unroll
        for (int kk = 0; kk < 2; ++kk) {
            bf16x8 av[4], bv[4];
            #pragma unroll
            for (int f = 0; f < 4; ++f) {
                av[f] = *(const bf16x8*)(Ac + ra[f] * 128 + (((kk << 2) | hi) ^ (ra[f] & 7)) * 16);
                bv[f] = *(const bf16x8*)(Bc + rb[f] * 128 + (((kk << 2) | hi) ^ (rb[f] & 7)) * 16);
            }
            #pragma unroll
            for (int fm = 0; fm < 4; ++fm)
                #pragma unroll
                for (int fn = 0; fn < 4; ++fn)
                    acc[fm][fn] = __builtin_amdgcn_mfma_f32_16x16x32_bf16(
                        av[fm], bv[fn], acc[fm][fn], 0, 0, 0);
        }
        __syncthreads();
    }

    #pragma unroll
    for (int fm = 0; fm < 4; ++fm) {
        #pragma unroll
        for (int r = 0; r < 4; ++r) {
            const int o = o0 + wm * 64 + fm * 16 + hi * 4 + r;
            const float bo = b_out[o];
            const size_t rowg = ((size_t)b * NC + o) * NN + n0;
            #pragma unroll
            for (int fn = 0; fn < 4; ++fn) {
                const size_t gi = rowg + wn * 64 + fn * 16 + lo;
                out[gi] = acc[fm][fn][r] + bo + x[gi];
            }
        }
    }
}

// ---------------------------------------------------------------------------
extern "C" void kernel_launch(void* const* d_in, const int* in_sizes, int n_in,
                              void* d_out, int out_size, void* d_ws, size_t ws_size,
                              hipStream_t stream) {
    const float* x     = (const float*)d_in[0];
    const float* w_in  = (const float*)d_in[1];
    const float* b_in  = (const float*)d_in[2];
    const float* w_out = (const float*)d_in[3];
    const float* b_out = (const float*)d_in[4];
    float* out = (float*)d_out;

    if (ws_size < (size_t)64 * 1024 * 1024) return;  // fail loud
    char* ws = (char*)d_ws;
    __hip_bfloat16* Qt = (__hip_bfloat16*)(ws);
    __hip_bfloat16* Kt = (__hip_bfloat16*)(ws + ((size_t)16 << 20));
    __hip_bfloat16* Vx = (__hip_bfloat16*)(ws + ((size_t)32 << 20));
    __hip_bfloat16* Xt = (__hip_bfloat16*)(ws + ((size_t)48 << 20));  // aliased as Ht
    __hip_bfloat16* Ht = Xt;  // Xt dead after qkv_gemm

    xpose_kernel<<<dim3(16, 4, 32), 256, 0, stream>>>(x, Xt);
    qkv_gemm_kernel<<<dim3(8, 6, 32), 256, 0, stream>>>(Xt, w_in, b_in, Qt, Kt, Vx);
    attn_kernel<<<dim3(8, 32), 512, 0, stream>>>(Qt, Kt, Vx, Ht);
    out_gemm_kernel<<<dim3(8, 2, 32), 256, 0, stream>>>(Ht, w_out, b_out, x, out);
}

// Round 4
// 105.963 us; speedup vs baseline: 3.2015x; 1.1062x over previous
//
#include <hip/hip_runtime.h>
#include <hip/hip_bf16.h>

typedef __attribute__((ext_vector_type(8))) short bf16x8;
typedef __attribute__((ext_vector_type(4))) float f32x4;

#define NB 32
#define NC 256
#define NN 1024

__device__ __forceinline__ unsigned pack2(float a, float b) {
    __hip_bfloat16 ha = __float2bfloat16(a), hb = __float2bfloat16(b);
    unsigned short ua = *(unsigned short*)&ha, ub = *(unsigned short*)&hb;
    return (unsigned)ua | ((unsigned)ub << 16);
}

// async global->LDS, 16B per lane; LDS dest = wave-uniform base + lane*16
__device__ __forceinline__ void glds16(const __hip_bfloat16* g, void* lds) {
    __builtin_amdgcn_global_load_lds(
        (const __attribute__((address_space(1))) unsigned int*)g,
        (__attribute__((address_space(3))) unsigned int*)lds, 16, 0, 0);
}

// ---------------------------------------------------------------------------
// Kernel 0: transpose+cast  x[b][c][n] f32 -> Xt[b][n][c] bf16
// ---------------------------------------------------------------------------
__global__ __launch_bounds__(256) void xpose_kernel(
    const float* __restrict__ x, __hip_bfloat16* __restrict__ Xt)
{
    __shared__ float Ls[64 * 67];
    const int t = threadIdx.x;
    const int n0 = blockIdx.x * 64, c0 = blockIdx.y * 64, b = blockIdx.z;
    const int cl = t >> 4, nl = (t & 15) * 4;
    const float* xb = x + ((size_t)b * NC + c0) * NN + n0;
    #pragma unroll
    for (int q4 = 0; q4 < 4; ++q4) {
        const int c = cl + q4 * 16;
        const float4 v = *(const float4*)(xb + (size_t)c * NN + nl);
        Ls[(nl + 0) * 67 + c] = v.x;
        Ls[(nl + 1) * 67 + c] = v.y;
        Ls[(nl + 2) * 67 + c] = v.z;
        Ls[(nl + 3) * 67 + c] = v.w;
    }
    __syncthreads();
    #pragma unroll
    for (int p = 0; p < 2; ++p) {
        const int idx = p * 256 + t, n = idx >> 3, cs = idx & 7;
        const float* r = &Ls[n * 67 + cs * 8];
        uint4 o;
        o.x = pack2(r[0], r[1]); o.y = pack2(r[2], r[3]);
        o.z = pack2(r[4], r[5]); o.w = pack2(r[6], r[7]);
        *(uint4*)(Xt + ((size_t)b * NN + n0 + n) * NC + c0 + cs * 8) = o;
    }
}

// ---------------------------------------------------------------------------
// Shared GEMM staging (element-traced swizzle; unchanged).
// ---------------------------------------------------------------------------
__device__ __forceinline__ void stage_ab(const __hip_bfloat16* __restrict__ Ag,
                                         const float* __restrict__ Bg,
                                         char* Ad, char* Bd, int ks, int t)
{
    const int srow = t >> 3, spch = t & 7;
    #pragma unroll
    for (int it = 0; it < 4; ++it) {
        const int row = it * 32 + srow;
        const int sw  = row & 7;
        glds16(Ag + (size_t)row * NC + ks * 64 + ((spch ^ sw) << 3),
               Ad + (it * 256 + t) * 16);
        const float* wp = Bg + (size_t)row * NC + ks * 64 + (spch << 3);
        const float4 u0 = *(const float4*)wp;
        const float4 u1 = *(const float4*)(wp + 4);
        uint4 pk;
        pk.x = pack2(u0.x, u0.y); pk.y = pack2(u0.z, u0.w);
        pk.z = pack2(u1.x, u1.y); pk.w = pack2(u1.z, u1.w);
        *(uint4*)(Bd + row * 128 + ((spch ^ sw) << 4)) = pk;
    }
}

// ---------------------------------------------------------------------------
// Kernel 1: QKV projection GEMM (bf16 MFMA) — unchanged.
// ---------------------------------------------------------------------------
__global__ __launch_bounds__(256, 2) void qkv_gemm_kernel(
    const __hip_bfloat16* __restrict__ Xt, const float* __restrict__ w_in,
    const float* __restrict__ b_in, __hip_bfloat16* __restrict__ Qt,
    __hip_bfloat16* __restrict__ Kt, __hip_bfloat16* __restrict__ Vx)
{
    __shared__ char smem[65536];
    char* const A0 = smem;
    char* const A1 = smem + 16384;
    char* const B0 = smem + 32768;
    char* const B1 = smem + 49152;

    const int t  = threadIdx.x;
    const int wv = t >> 6, ln = t & 63, lo = ln & 15, hi = ln >> 4;
    const int wm = wv >> 1, wn = wv & 1;
    const int n0 = blockIdx.x * 128, o0 = blockIdx.y * 128, b = blockIdx.z;

    const __hip_bfloat16* Ag = Xt + ((size_t)b * NN + n0) * NC;
    const float* Bg = w_in + (size_t)o0 * NC;

    f32x4 acc[4][4];
    #pragma unroll
    for (int i = 0; i < 4; ++i)
        #pragma unroll
        for (int j = 0; j < 4; ++j) acc[i][j] = (f32x4){0.f, 0.f, 0.f, 0.f};

    int ra[4], rb[4];
    #pragma unroll
    for (int f = 0; f < 4; ++f) { ra[f] = wm * 64 + f * 16 + lo; rb[f] = wn * 64 + f * 16 + lo; }

    stage_ab(Ag, Bg, A0, B0, 0, t);
    __syncthreads();
    #pragma unroll
    for (int ks = 0; ks < 4; ++ks) {
        char* Ac = (ks & 1) ? A1 : A0;
        char* Bc = (ks & 1) ? B1 : B0;
        if (ks < 3)
            stage_ab(Ag, Bg, (ks & 1) ? A0 : A1, (ks & 1) ? B0 : B1, ks + 1, t);
        #pragma unroll
        for (int kk = 0; kk < 2; ++kk) {
            bf16x8 av[4], bv[4];
            #pragma unroll
            for (int f = 0; f < 4; ++f) {
                av[f] = *(const bf16x8*)(Ac + ra[f] * 128 + (((kk << 2) | hi) ^ (ra[f] & 7)) * 16);
                bv[f] = *(const bf16x8*)(Bc + rb[f] * 128 + (((kk << 2) | hi) ^ (rb[f] & 7)) * 16);
            }
            #pragma unroll
            for (int fm = 0; fm < 4; ++fm)
                #pragma unroll
                for (int fn = 0; fn < 4; ++fn)
                    acc[fm][fn] = __builtin_amdgcn_mfma_f32_16x16x32_bf16(
                        av[fm], bv[fn], acc[fm][fn], 0, 0, 0);
        }
        __syncthreads();
    }

    float bias[4];
    #pragma unroll
    for (int fn = 0; fn < 4; ++fn) bias[fn] = b_in[o0 + wn * 64 + fn * 16 + lo];

    __hip_bfloat16* Ls = (__hip_bfloat16*)smem;  // [128][136] bf16
    if (o0 < 512) {
        #pragma unroll
        for (int fm = 0; fm < 4; ++fm)
            #pragma unroll
            for (int fn = 0; fn < 4; ++fn)
                #pragma unroll
                for (int r = 0; r < 4; ++r)
                    Ls[(wm * 64 + fm * 16 + hi * 4 + r) * 136 + wn * 64 + fn * 16 + lo] =
                        __float2bfloat16(acc[fm][fn][r] + bias[fn]);
        __syncthreads();
        __hip_bfloat16* dst = (o0 < 256) ? Qt : Kt;
        const int oc = (o0 < 256) ? o0 : o0 - 256;
        #pragma unroll
        for (int p = 0; p < 8; ++p) {
            const int idx = p * 256 + t, row = idx >> 4, ch = idx & 15;
            *(uint4*)(dst + ((size_t)b * NN + n0 + row) * NC + oc + ch * 8) =
                *(const uint4*)&Ls[row * 136 + ch * 8];
        }
    } else {
        #pragma unroll
        for (int fm = 0; fm < 4; ++fm)
            #pragma unroll
            for (int fn = 0; fn < 4; ++fn)
                #pragma unroll
                for (int r = 0; r < 4; ++r)
                    Ls[(wn * 64 + fn * 16 + lo) * 136 + wm * 64 + fm * 16 + hi * 4 + r] =
                        __float2bfloat16(acc[fm][fn][r] + bias[fn]);
        __syncthreads();
        #pragma unroll
        for (int p = 0; p < 8; ++p) {
            const int idx = p * 256 + t, row = idx >> 4, ch = idx & 15;
            *(uint4*)(Vx + ((size_t)b * NC + (o0 - 512) + row) * NN + n0 + ch * 8) =
                *(const uint4*)&Ls[row * 136 + ch * 8];
        }
    }
}

// ---------------------------------------------------------------------------
// Kernel 2: flash attention v3 — swapped QK^T, fully in-register P.
// sf = mfma(K, Q): lane (lo,hi) holds S^T for q-row lo, keys mf*16+hi*4+r.
// Softmax: in-lane 16-max/sum + 2 shfl_xor (16,32). P redistributed to the
// PV A-fragment via 16 ds_bpermute + selects (no LDS, no lgkm stall).
// Redistribution trace: lane(lo=3,hi=2), k2=1 needs keys 48..55 of q-row 3.
//   mf=2k2+(hi>>1)=3, srcA=lane(3,0)=3, srcB=lane(3,1)=19, sel=hi&2=1:
//   b0=pu[3][0]@3 = keys 48,49; b1=50,51; d0=pu[3][0]@19 = keys 52,53; d1=54,55. OK
// Defer-max with m init 0 (scores ~N(0,1); guarded rescale kept for safety).
// grid (8,32), 512 thr; LDS 128K: K[2][64][256] | V[2][256][64] (swizzled).
// ---------------------------------------------------------------------------
__device__ __forceinline__ void attn_stage(const __hip_bfloat16* __restrict__ Kbase,
                                           const __hip_bfloat16* __restrict__ Vbase,
                                           char* Kd, char* Vd, int m0, int t)
{
    #pragma unroll
    for (int p = 0; p < 4; ++p) {
        const int idx = p * 512 + t;
        const int row = idx >> 5, pc = idx & 31;
        const int sc = (pc & 24) | ((pc ^ row) & 7);
        glds16(Kbase + (size_t)(m0 + row) * NC + sc * 8, Kd + idx * 16);
    }
    #pragma unroll
    for (int p = 0; p < 4; ++p) {
        const int idx = p * 512 + t;
        const int row = idx >> 3, pc = idx & 7;
        const int sc = pc ^ (row & 7);
        glds16(Vbase + (size_t)row * NN + m0 + sc * 8, Vd + idx * 16);
    }
}

__global__ __launch_bounds__(512, 2) void attn_kernel(
    const __hip_bfloat16* __restrict__ Qt, const __hip_bfloat16* __restrict__ Kt,
    const __hip_bfloat16* __restrict__ Vx, __hip_bfloat16* __restrict__ Ht)
{
    __shared__ char smem[131072];   // 2*32768 K | 2*32768 V

    const int t  = threadIdx.x;
    const int wv = t >> 6, ln = t & 63, lo = ln & 15, hi = ln >> 4;
    const int wid = blockIdx.x + 8 * blockIdx.y;
    const int swz = (wid & 7) * 32 + (wid >> 3);       // XCD gets 4 batches
    const int qb = swz & 7, b = swz >> 3;
    const int n0 = qb * 128;
    const float scale = 0.0625f;  // 1/sqrt(256)

    const __hip_bfloat16* Kbase = Kt + (size_t)b * NN * NC;
    const __hip_bfloat16* Vbase = Vx + (size_t)b * NC * NN;

    // Q fragments: wave's 16 rows; row=lo, k = kk*32+hi*8+j  (B operand)
    const __hip_bfloat16* qp = Qt + ((size_t)b * NN + n0 + wv * 16 + lo) * NC;
    bf16x8 qf[8];
    #pragma unroll
    for (int kk = 0; kk < 8; ++kk)
        qf[kk] = *(const bf16x8*)(qp + kk * 32 + hi * 8);

    f32x4 acc[16];
    #pragma unroll
    for (int cf = 0; cf < 16; ++cf) acc[cf] = (f32x4){0.f, 0.f, 0.f, 0.f};
    float mr = 0.f;   // running max for q-row lo (defer-max; scores are O(1))
    float sr = 0.f;   // running denom for q-row lo

    attn_stage(Kbase, Vbase, smem, smem + 65536, 0, t);
    __syncthreads();   // drains vmcnt -> tile 0 resident

    for (int mc = 0; mc < 16; ++mc) {
        const int cb = mc & 1;
        char* const Kc = smem + cb * 32768;
        char* const Vc = smem + 65536 + cb * 32768;
        if (mc < 15)
            attn_stage(Kbase, Vbase, smem + (cb ^ 1) * 32768,
                       smem + 65536 + (cb ^ 1) * 32768, (mc + 1) * 64, t);

        // S^T = K Q^T : sf[mf] -> keys mf*16+hi*4+r, q-row lo
        f32x4 sf[4];
        #pragma unroll
        for (int mf = 0; mf < 4; ++mf) sf[mf] = (f32x4){0.f, 0.f, 0.f, 0.f};
        __builtin_amdgcn_s_setprio(1);
        #pragma unroll
        for (int mf = 0; mf < 4; ++mf) {
            const int row = mf * 16 + lo;
            #pragma unroll
            for (int kk = 0; kk < 8; ++kk) {
                const int c  = kk * 4 + hi;
                const int pc = (c & 24) | ((c ^ row) & 7);
                bf16x8 kf = *(const bf16x8*)(Kc + row * 512 + pc * 16);
                sf[mf] = __builtin_amdgcn_mfma_f32_16x16x32_bf16(kf, qf[kk], sf[mf], 0, 0, 0);
            }
        }
        __builtin_amdgcn_s_setprio(0);

        // row max (guard only; rescale ~never fires with m=0 init)
        float tm = sf[0][0];
        #pragma unroll
        for (int mf = 0; mf < 4; ++mf)
            #pragma unroll
            for (int r = 0; r < 4; ++r) tm = fmaxf(tm, sf[mf][r]);
        tm = fmaxf(tm, __shfl_xor(tm, 16, 64));
        tm = fmaxf(tm, __shfl_xor(tm, 32, 64));
        tm *= scale;
        if (__any(tm > mr + 8.f)) {
            const float mn = fmaxf(mr, tm);
            const float al = __expf(mr - mn);
            mr = mn;
            sr *= al;
            float al4[4];
            #pragma unroll
            for (int r = 0; r < 4; ++r) al4[r] = __shfl(al, hi * 4 + r, 64);
            #pragma unroll
            for (int cf = 0; cf < 16; ++cf)
                #pragma unroll
                for (int r = 0; r < 4; ++r) acc[cf][r] *= al4[r];
        }

        // P = exp(S*scale - m), row sum
        float p[4][4];
        float s = 0.f;
        #pragma unroll
        for (int mf = 0; mf < 4; ++mf)
            #pragma unroll
            for (int r = 0; r < 4; ++r) {
                p[mf][r] = __expf(sf[mf][r] * scale - mr);
                s += p[mf][r];
            }
        s += __shfl_xor(s, 16, 64);
        s += __shfl_xor(s, 32, 64);
        sr += s;

        // pack P -> bf16 pairs; redistribute to PV A-fragments (in-register)
        unsigned pu[4][2];
        #pragma unroll
        for (int mf = 0; mf < 4; ++mf) {
            pu[mf][0] = pack2(p[mf][0], p[mf][1]);
            pu[mf][1] = pack2(p[mf][2], p[mf][3]);
        }
        const int srcA = lo + ((hi & 1) << 5);   // lane (lo, 2*(hi&1))
        const int srcB = srcA + 16;
        const bool sel = (hi & 2) != 0;          // mf = 2*k2 + (hi>>1)
        bf16x8 pa[2];
        #pragma unroll
        for (int k2 = 0; k2 < 2; ++k2) {
            const int a0 = __shfl((int)pu[2 * k2][0], srcA, 64);
            const int a1 = __shfl((int)pu[2 * k2][1], srcA, 64);
            const int b0 = __shfl((int)pu[2 * k2 + 1][0], srcA, 64);
            const int b1 = __shfl((int)pu[2 * k2 + 1][1], srcA, 64);
            const int c0 = __shfl((int)pu[2 * k2][0], srcB, 64);
            const int c1 = __shfl((int)pu[2 * k2][1], srcB, 64);
            const int d0 = __shfl((int)pu[2 * k2 + 1][0], srcB, 64);
            const int d1 = __shfl((int)pu[2 * k2 + 1][1], srcB, 64);
            union { int i[4]; bf16x8 v; } u;
            u.i[0] = sel ? b0 : a0;
            u.i[1] = sel ? b1 : a1;
            u.i[2] = sel ? d0 : c0;
            u.i[3] = sel ? d1 : c1;
            pa[k2] = u.v;
        }

        // H^T += P V^T
        __builtin_amdgcn_s_setprio(1);
        #pragma unroll
        for (int k2 = 0; k2 < 2; ++k2) {
            #pragma unroll
            for (int cf = 0; cf < 16; ++cf) {
                const int row = cf * 16 + lo;
                const int pc  = (k2 * 4 + hi) ^ (row & 7);
                bf16x8 vf = *(const bf16x8*)(Vc + row * 128 + pc * 16);
                acc[cf] = __builtin_amdgcn_mfma_f32_16x16x32_bf16(pa[k2], vf, acc[cf], 0, 0, 0);
            }
        }
        __builtin_amdgcn_s_setprio(0);
        __syncthreads();  // drains vmcnt(0): next tile resident; buffers swappable
    }

    // epilogue: inv per q-row (held at lanes 0..15) -> broadcast to C layout
    const float invr = 1.0f / sr;
    float inv4[4];
    #pragma unroll
    for (int r = 0; r < 4; ++r) inv4[r] = __shfl(invr, hi * 4 + r, 64);

    __hip_bfloat16* W = (__hip_bfloat16*)(smem + wv * 8192);  // wave-private [16][256]
    #pragma unroll
    for (int cf = 0; cf < 16; ++cf)
        #pragma unroll
        for (int r = 0; r < 4; ++r)
            W[(hi * 4 + r) * 256 + cf * 16 + lo] = __float2bfloat16(acc[cf][r] * inv4[r]);
    asm volatile("s_waitcnt lgkmcnt(0)" ::: "memory");
    __builtin_amdgcn_sched_barrier(0);
    __hip_bfloat16* hrow0 = Ht + ((size_t)b * NN + n0 + wv * 16) * NC;
    #pragma unroll
    for (int pq = 0; pq < 8; ++pq) {
        const int idx = pq * 64 + ln;
        const int row = idx >> 5, ch = idx & 31;
        *(uint4*)(hrow0 + (size_t)row * NC + ch * 8) = *(const uint4*)&W[row * 256 + ch * 8];
    }
}

// ---------------------------------------------------------------------------
// Kernel 3: output projection GEMM (bf16 MFMA) + bias + skip — unchanged.
// ---------------------------------------------------------------------------
__global__ __launch_bounds__(256, 2) void out_gemm_kernel(
    const __hip_bfloat16* __restrict__ Ht, const float* __restrict__ w_out,
    const float* __restrict__ b_out, const float* __restrict__ x,
    float* __restrict__ out)
{
    __shared__ char smem[65536];
    char* const A0 = smem;
    char* const A1 = smem + 16384;
    char* const B0 = smem + 32768;
    char* const B1 = smem + 49152;

    const int t  = threadIdx.x;
    const int wv = t >> 6, ln = t & 63, lo = ln & 15, hi = ln >> 4;
    const int wm = wv >> 1, wn = wv & 1;
    const int n0 = blockIdx.x * 128, o0 = blockIdx.y * 128, b = blockIdx.z;

    const float* Ag = w_out + (size_t)o0 * NC;
    const __hip_bfloat16* Bg = Ht + ((size_t)b * NN + n0) * NC;

    f32x4 acc[4][4];
    #pragma unroll
    for (int i = 0; i < 4; ++i)
        #pragma unroll
        for (int j = 0; j < 4; ++j) acc[i][j] = (f32x4){0.f, 0.f, 0.f, 0.f};

    int ra[4], rb[4];
    #pragma unroll
    for (int f = 0; f < 4; ++f) { ra[f] = wm * 64 + f * 16 + lo; rb[f] = wn * 64 + f * 16 + lo; }

    stage_ab(Bg, Ag, B0, A0, 0, t);
    __syncthreads();
    #pragma unroll
    for (int ks = 0; ks < 4; ++ks) {
        char* Ac = (ks & 1) ? A1 : A0;
        char* Bc = (ks & 1) ? B1 : B0;
        if (ks < 3)
            stage_ab(Bg, Ag, (ks & 1) ? B0 : B1, (ks & 1) ? A0 : A1, ks + 1, t);
        #pragma unroll
        for (int kk = 0; kk < 2; ++kk) {
            bf16x8 av[4], bv[4];
            #pragma unroll
            for (int f = 0; f < 4; ++f) {
                av[f] = *(const bf16x8*)(Ac + ra[f] * 128 + (((kk << 2) | hi) ^ (ra[f] & 7)) * 16);
                bv[f] = *(const bf16x8*)(Bc + rb[f] * 128 + (((kk << 2) | hi) ^ (rb[f] & 7)) * 16);
            }
            #pragma unroll
            for (int fm = 0; fm < 4; ++fm)
                #pragma unroll
                for (int fn = 0; fn < 4; ++fn)
                    acc[fm][fn] = __builtin_amdgcn_mfma_f32_16x16x32_bf16(
                        av[fm], bv[fn], acc[fm][fn], 0, 0, 0);
        }
        __syncthreads();
    }

    #pragma unroll
    for (int fm = 0; fm < 4; ++fm) {
        #pragma unroll
        for (int r = 0; r < 4; ++r) {
            const int o = o0 + wm * 64 + fm * 16 + hi * 4 + r;
            const float bo = b_out[o];
            const size_t rowg = ((size_t)b * NC + o) * NN + n0;
            #pragma unroll
            for (int fn = 0; fn < 4; ++fn) {
                const size_t gi = rowg + wn * 64 + fn * 16 + lo;
                out[gi] = acc[fm][fn][r] + bo + x[gi];
            }
        }
    }
}

// ---------------------------------------------------------------------------
extern "C" void kernel_launch(void* const* d_in, const int* in_sizes, int n_in,
                              void* d_out, int out_size, void* d_ws, size_t ws_size,
                              hipStream_t stream) {
    const float* x     = (const float*)d_in[0];
    const float* w_in  = (const float*)d_in[1];
    const float* b_in  = (const float*)d_in[2];
    const float* w_out = (const float*)d_in[3];
    const float* b_out = (const float*)d_in[4];
    float* out = (float*)d_out;

    if (ws_size < (size_t)64 * 1024 * 1024) return;  // fail loud
    char* ws = (char*)d_ws;
    __hip_bfloat16* Qt = (__hip_bfloat16*)(ws);
    __hip_bfloat16* Kt = (__hip_bfloat16*)(ws + ((size_t)16 << 20));
    __hip_bfloat16* Vx = (__hip_bfloat16*)(ws + ((size_t)32 << 20));
    __hip_bfloat16* Xt = (__hip_bfloat16*)(ws + ((size_t)48 << 20));  // aliased as Ht
    __hip_bfloat16* Ht = Xt;  // Xt dead after qkv_gemm

    xpose_kernel<<<dim3(16, 4, 32), 256, 0, stream>>>(x, Xt);
    qkv_gemm_kernel<<<dim3(8, 6, 32), 256, 0, stream>>>(Xt, w_in, b_in, Qt, Kt, Vx);
    attn_kernel<<<dim3(8, 32), 512, 0, stream>>>(Qt, Kt, Vx, Ht);
    out_gemm_kernel<<<dim3(8, 2, 32), 256, 0, stream>>>(Ht, w_out, b_out, x, out);
}